// Round 7
// baseline (123.572 us; speedup 1.0000x reference)
//
#include <hip/hip_runtime.h>
#include <hip/hip_bf16.h>

// BiLingual embedding-bag-sum, R7 (= R6 with compile fix): merged bf16
// pipeline, 2 kernels.
//   out[t,b,d] = sum_s emb_t[idx_t[b,s], d]   (B=4096, S=200, D=64, vocab=100K)
//
// Established model (R2/R4/R5): gather cost tracks cache-LINES processed
// (~10.9 cyc/line/CU in TA/TCP), independent of cache level (R2 L3-served ==
// R4 L2-resident), MLP (R1==R2) and occupancy. bf16 rows = 128 B = 1 line
// (R5: halved lines -> halved gather time). Floor: converts 77 MB streaming
// ~12 us + gathers 1.64M lines ~29 us. R7 removes the remaining slack:
//   K1 convert_both: both tables fp32->bf16 (RTNE), nontemporal, one launch.
//   K2 gather_both:  one wave per (t,b) bag, LDS-staged indices, quarter-wave
//                    gather (4 rows x 16 lanes x 8B per instr),
//                    shuffle-reduce, barrier-free coalesced store.
// ws = 25.6 MB bf16 tables; fallback to fp32 monolithic if ws too small.
// NOTE: __builtin_nontemporal_* requires ext_vector_type pointers, not
// HIP_vector_type (float4/uint2) -- that was R6's compile failure.

#define BB 4096
#define SS 200
#define DD 64
#define VOCAB 100000
#define TBL_U2 ((size_t)VOCAB * DD / 4)   // 8B-granules per bf16 table

typedef float    vfloat4 __attribute__((ext_vector_type(4)));
typedef unsigned vuint2  __attribute__((ext_vector_type(2)));

// ---- K1: both tables fp32 -> packed bf16 (RTNE), streaming ----
__global__ __launch_bounds__(256) void convert_both(
    const float* __restrict__ src_pri,
    const float* __restrict__ src_sec,
    vuint2* __restrict__ dst)         // [2][VOCAB*DD/4]
{
    const int per_table = (VOCAB * DD / 4) / 256;        // 6250 blocks/table
    const int t = (int)blockIdx.x >= per_table;
    const size_t g = ((size_t)blockIdx.x - (size_t)t * per_table) * 256 + threadIdx.x;

    const float* src = t ? src_sec : src_pri;
    const vfloat4 v = __builtin_nontemporal_load((const vfloat4*)src + g);
    const unsigned u0 = __bfloat16_as_ushort(__float2bfloat16(v.x));
    const unsigned u1 = __bfloat16_as_ushort(__float2bfloat16(v.y));
    const unsigned u2 = __bfloat16_as_ushort(__float2bfloat16(v.z));
    const unsigned u3 = __bfloat16_as_ushort(__float2bfloat16(v.w));
    vuint2 o;
    o.x = u0 | (u1 << 16);
    o.y = u2 | (u3 << 16);
    __builtin_nontemporal_store(o, dst + (size_t)t * TBL_U2 + g);
}

// ---- K2: gather-sum over bf16 rows, both tables. One wave per (t,b). ----
__global__ __launch_bounds__(256) void gather_both(
    const int* __restrict__ idx_pri,   // [BB][SS]
    const int* __restrict__ idx_sec,   // [BB][SS]
    const vuint2* __restrict__ emb,    // [2][VOCAB][16] packed bf16 rows
    float* __restrict__ out)           // [2][BB][DD]
{
    __shared__ int sidx[4][SS];

    const int tid  = (int)threadIdx.x;
    const int w    = tid >> 6;
    const int lane = tid & 63;
    const int wave = (int)blockIdx.x * 4 + w;
    const int t    = wave >> 12;           // 0 = pri, 1 = sec
    const int b    = wave & (BB - 1);

    // Stage this wave's 200 indices: 50 int4 loads, lanes 0..49.
    const int* row_idx = (t ? idx_sec : idx_pri) + b * SS;
    if (lane < SS / 4) {
        const int4 v = ((const int4*)row_idx)[lane];
        sidx[w][lane * 4 + 0] = v.x;
        sidx[w][lane * 4 + 1] = v.y;
        sidx[w][lane * 4 + 2] = v.z;
        sidx[w][lane * 4 + 3] = v.w;
    }
    __syncthreads();

    const int q   = lane >> 4;     // quarter-wave: which row in the group of 4
    const int l16 = lane & 15;     // 8B slot within the 128B row
    const vuint2* et = emb + (size_t)t * TBL_U2;

    float4 acc = make_float4(0.f, 0.f, 0.f, 0.f);

    #pragma unroll 10
    for (int s0 = 0; s0 < SS; s0 += 4) {
        const int i = sidx[w][s0 + q];
        const vuint2 v = et[(size_t)i * 16 + l16];   // 8B: bf16 x4
        acc.x += __uint_as_float(v.x << 16);
        acc.y += __uint_as_float(v.x & 0xffff0000u);
        acc.z += __uint_as_float(v.y << 16);
        acc.w += __uint_as_float(v.y & 0xffff0000u);
    }

    // Reduce the 4 quarter-wave partials.
    acc.x += __shfl_down(acc.x, 32);
    acc.y += __shfl_down(acc.y, 32);
    acc.z += __shfl_down(acc.z, 32);
    acc.w += __shfl_down(acc.w, 32);
    acc.x += __shfl_down(acc.x, 16);
    acc.y += __shfl_down(acc.y, 16);
    acc.z += __shfl_down(acc.z, 16);
    acc.w += __shfl_down(acc.w, 16);

    if (lane < 16) {
        ((float4*)(out + ((size_t)t * BB + b) * DD))[l16] = acc;
    }
}

// ---- fallback (R2): fp32 monolithic, if ws too small ----
__global__ __launch_bounds__(256) void bilingual_embed_sum(
    const int* __restrict__ idx_pri,
    const int* __restrict__ idx_sec,
    const float* __restrict__ emb_pri,
    const float* __restrict__ emb_sec,
    float* __restrict__ out)
{
    __shared__ int sidx[4][SS];
    const int w    = (int)(threadIdx.x >> 6);
    const int lane = (int)(threadIdx.x & 63);
    const int wave = (int)(blockIdx.x * 4 + w);
    const int table = wave >> 12;
    const int b     = wave & (BB - 1);

    const int*   idx = table ? idx_sec : idx_pri;
    const float* emb = table ? emb_sec : emb_pri;
    float* outp = out + (size_t)table * BB * DD + (size_t)b * DD;

    const int* row_idx = idx + b * SS;
    if (lane < SS / 4) {
        const int4 v = ((const int4*)row_idx)[lane];
        sidx[w][lane * 4 + 0] = v.x;
        sidx[w][lane * 4 + 1] = v.y;
        sidx[w][lane * 4 + 2] = v.z;
        sidx[w][lane * 4 + 3] = v.w;
    }
    __syncthreads();

    const int q   = lane >> 4;
    const int l16 = lane & 15;
    float4 acc = make_float4(0.f, 0.f, 0.f, 0.f);

    #pragma unroll 10
    for (int s0 = 0; s0 < SS; s0 += 4) {
        const int i = sidx[w][s0 + q];
        const float4 v = ((const float4*)(emb + (size_t)i * DD))[l16];
        acc.x += v.x; acc.y += v.y; acc.z += v.z; acc.w += v.w;
    }

    acc.x += __shfl_down(acc.x, 32);
    acc.y += __shfl_down(acc.y, 32);
    acc.z += __shfl_down(acc.z, 32);
    acc.w += __shfl_down(acc.w, 32);
    acc.x += __shfl_down(acc.x, 16);
    acc.y += __shfl_down(acc.y, 16);
    acc.z += __shfl_down(acc.z, 16);
    acc.w += __shfl_down(acc.w, 16);

    if (lane < 16) ((float4*)outp)[l16] = acc;
}

extern "C" void kernel_launch(void* const* d_in, const int* in_sizes, int n_in,
                              void* d_out, int out_size, void* d_ws, size_t ws_size,
                              hipStream_t stream) {
    const int*   idx_pri = (const int*)d_in[0];
    const int*   idx_sec = (const int*)d_in[1];
    const float* emb_pri = (const float*)d_in[2];
    const float* emb_sec = (const float*)d_in[3];
    float* out = (float*)d_out;

    const size_t ws_need = (size_t)2 * VOCAB * DD * 2;   // 25.6 MB bf16 tables

    if (ws_size >= ws_need) {
        vuint2* tbl = (vuint2*)d_ws;
        const int conv_grid   = 2 * (VOCAB * DD / 4) / 256;   // 12500
        const int gather_grid = (2 * BB) / 4;                 // 2048

        convert_both<<<conv_grid, 256, 0, stream>>>(emb_pri, emb_sec, tbl);
        gather_both<<<gather_grid, 256, 0, stream>>>(idx_pri, idx_sec, tbl, out);
    } else {
        bilingual_embed_sum<<<(2 * BB) / 4, 256, 0, stream>>>(
            idx_pri, idx_sec, emb_pri, emb_sec, out);
    }
}